// Round 1
// baseline (60.194 us; speedup 1.0000x reference)
//
#include <hip/hip_runtime.h>

#define D_EMB   64
#define D_HID   128
#define NUM_EL  118

// Kernel 1: per-element energy table. One block per atomic number z,
// 128 threads = one per hidden unit. Whole MLP fits in LDS.
__global__ void mace_etab_kernel(const float* __restrict__ embed,
                                 const float* __restrict__ W1, const float* __restrict__ b1,
                                 const float* __restrict__ W2, const float* __restrict__ b2,
                                 const float* __restrict__ W3, const float* __restrict__ b3,
                                 float* __restrict__ Etab) {
    __shared__ float h[D_EMB];
    __shared__ float x1[D_HID];
    __shared__ float red[D_HID];
    const int z = blockIdx.x;
    const int t = threadIdx.x;

    if (t < D_EMB) h[t] = embed[z * D_EMB + t];
    __syncthreads();

    // x1 = silu(h @ W1 + b1)   ; W1 stored (in=64, out=128) row-major
    float acc = b1[t];
    #pragma unroll
    for (int k = 0; k < D_EMB; ++k)
        acc = fmaf(h[k], W1[k * D_HID + t], acc);
    x1[t] = acc / (1.0f + expf(-acc));
    __syncthreads();

    // x2 = silu(x1 @ W2 + b2)
    float acc2 = b2[t];
    #pragma unroll
    for (int k = 0; k < D_HID; ++k)
        acc2 = fmaf(x1[k], W2[k * D_HID + t], acc2);
    float s2 = acc2 / (1.0f + expf(-acc2));
    red[t] = s2 * W3[t];          // per-hidden contribution to (x2 @ W3)
    __syncthreads();

    // tree-reduce 128 -> 1
    for (int off = D_HID / 2; off > 0; off >>= 1) {
        if (t < off) red[t] += red[t + off];
        __syncthreads();
    }
    if (t == 0) Etab[z] = red[0] + b3[0];
}

// Kernel 2: energy[b] += E[z_i], exploiting sorted batch ids.
// N and the grid stride are multiples of 64, so every wave iteration is
// fully active -> the shuffle reduce is safe.
__global__ void mace_scatter_kernel(const int* __restrict__ z,
                                    const int* __restrict__ batch,
                                    const float* __restrict__ Etab,
                                    float* __restrict__ energy,
                                    int n) {
    const int stride = gridDim.x * blockDim.x;
    for (int i = blockIdx.x * blockDim.x + threadIdx.x; i < n; i += stride) {
        const int b = batch[i];
        float e = Etab[z[i]];
        const int b0 = __builtin_amdgcn_readfirstlane(b);
        const unsigned long long same = __ballot(b == b0);
        if (same == ~0ULL) {
            // whole wave in one segment: 64-lane butterfly-free down-reduce
            #pragma unroll
            for (int off = 32; off > 0; off >>= 1)
                e += __shfl_down(e, off, 64);
            if ((threadIdx.x & 63) == 0)
                atomicAdd(&energy[b0], e);
        } else {
            // segment boundary inside the wave (rare: ~1024 waves of 15625)
            atomicAdd(&energy[b], e);
        }
    }
}

extern "C" void kernel_launch(void* const* d_in, const int* in_sizes, int n_in,
                              void* d_out, int out_size, void* d_ws, size_t ws_size,
                              hipStream_t stream) {
    // setup_inputs order:
    // 0 positions, 1 embed, 2 W1, 3 b1, 4 W2, 5 b2, 6 W3, 7 b3,
    // 8 atomic_numbers, 9 batch
    const float* embed = (const float*)d_in[1];
    const float* W1    = (const float*)d_in[2];
    const float* b1    = (const float*)d_in[3];
    const float* W2    = (const float*)d_in[4];
    const float* b2    = (const float*)d_in[5];
    const float* W3    = (const float*)d_in[6];
    const float* b3    = (const float*)d_in[7];
    const int*   z     = (const int*)d_in[8];
    const int*   batch = (const int*)d_in[9];
    const int    n     = in_sizes[8];          // 1,000,000

    float* energy = (float*)d_out;             // [B] then forces [n*3], all f32
    float* Etab   = (float*)d_ws;              // 118 floats of scratch

    // Zero everything: forces are identically zero; energy is atomically
    // accumulated on top of zero. (memset is graph-capture safe.)
    hipMemsetAsync(d_out, 0, (size_t)out_size * sizeof(float), stream);

    mace_etab_kernel<<<NUM_EL, D_HID, 0, stream>>>(embed, W1, b1, W2, b2, W3, b3, Etab);
    mace_scatter_kernel<<<2048, 256, 0, stream>>>(z, batch, Etab, energy, n);
}

// Round 2
// 15.035 us; speedup vs baseline: 4.0037x; 4.0037x over previous
//
#include <hip/hip_runtime.h>

#define D_EMB   64
#define D_HID   128
#define NUM_EL  118

// ---------------------------------------------------------------------------
// Kernel 1: per-element energy table. One block per atomic number z,
// 128 threads = one per hidden unit. Whole MLP fits in LDS.
// ---------------------------------------------------------------------------
__global__ void mace_etab_kernel(const float* __restrict__ embed,
                                 const float* __restrict__ W1, const float* __restrict__ b1,
                                 const float* __restrict__ W2, const float* __restrict__ b2,
                                 const float* __restrict__ W3, const float* __restrict__ b3,
                                 float* __restrict__ Etab) {
    __shared__ float h[D_EMB];
    __shared__ float x1[D_HID];
    __shared__ float wsum[2];
    const int z = blockIdx.x;
    const int t = threadIdx.x;

    if (t < D_EMB) h[t] = embed[z * D_EMB + t];
    __syncthreads();

    // x1 = silu(h @ W1 + b1)   ; W1 stored (in=64, out=128) row-major
    float acc = b1[t];
    #pragma unroll
    for (int k = 0; k < D_EMB; ++k)
        acc = fmaf(h[k], W1[k * D_HID + t], acc);
    x1[t] = acc / (1.0f + expf(-acc));
    __syncthreads();

    // x2 = silu(x1 @ W2 + b2); contribution to dot(x2, W3)
    float acc2 = b2[t];
    #pragma unroll
    for (int k = 0; k < D_HID; ++k)
        acc2 = fmaf(x1[k], W2[k * D_HID + t], acc2);
    float s2 = acc2 / (1.0f + expf(-acc2));
    float r = s2 * W3[t];

    // wave shuffle reduce (2 waves of 64), then combine
    #pragma unroll
    for (int off = 32; off > 0; off >>= 1)
        r += __shfl_down(r, off, 64);
    if ((t & 63) == 0) wsum[t >> 6] = r;
    __syncthreads();
    if (t == 0) Etab[z] = wsum[0] + wsum[1] + b3[0];
}

// ---------------------------------------------------------------------------
// Cooperative 64-ary lower_bound: all 64 lanes of the calling wave
// participate. Returns first idx in [0,n] with arr[idx] >= target.
// ~log64(n) = 4 probe rounds for n = 1e6.
// ---------------------------------------------------------------------------
__device__ __forceinline__ int lower_bound_wave(const int* __restrict__ arr,
                                                int n, int target) {
    int lo = 0, hi = n;                 // answer in [lo, hi]
    const int lane = threadIdx.x & 63;
    while (hi > lo) {
        const int range = hi - lo;
        const int step  = (range + 63) >> 6;      // ceil(range/64)
        const int pos   = lo + lane * step;
        const bool lt   = (pos < hi) && (arr[pos] < target);
        const unsigned long long m = __ballot(lt);
        const int k = __popcll(m);                // prefix length (arr sorted)
        if (k == 0) { hi = lo; break; }           // arr[lo] >= target
        const int new_lo = lo + (k - 1) * step + 1;
        int new_hi = lo + k * step;
        if (new_hi > hi) new_hi = hi;
        lo = new_lo; hi = new_hi;
    }
    return lo;
}

// ---------------------------------------------------------------------------
// Kernel 2: one block per molecule b. Binary-search the (sorted) batch array
// for the segment bounds, sum Etab[z[i]] over the segment, store energy[b]
// directly (no atomics). Also zeroes the force output (grid-strided float4).
// ---------------------------------------------------------------------------
__global__ __launch_bounds__(256)
void mace_segsum_kernel(const int* __restrict__ z,
                        const int* __restrict__ batch,
                        const float* __restrict__ EtabG,
                        float* __restrict__ energy,
                        float4* __restrict__ forces4,  // 3N/4 float4s, to zero
                        int n, int nf4) {
    __shared__ float etab_s[NUM_EL];
    __shared__ int   bounds[2];
    __shared__ float wsum[4];
    const int b = blockIdx.x;
    const int t = threadIdx.x;
    const int w = t >> 6;

    if (t < NUM_EL) etab_s[t] = EtabG[t];

    // zero forces: grid-strided float4 stores (3 iters/thread)
    const int gstride = gridDim.x * blockDim.x;
    for (int i = b * blockDim.x + t; i < nf4; i += gstride)
        forces4[i] = make_float4(0.f, 0.f, 0.f, 0.f);

    if (w == 0) {
        const int s = lower_bound_wave(batch, n, b);
        if ((t & 63) == 0) bounds[0] = s;
    } else if (w == 1) {
        const int e = lower_bound_wave(batch, n, b + 1);
        if ((t & 63) == 0) bounds[1] = e;
    }
    __syncthreads();

    const int start = bounds[0], end = bounds[1];
    float acc = 0.f;
    for (int i = start + t; i < end; i += 256)
        acc += etab_s[z[i]];

    #pragma unroll
    for (int off = 32; off > 0; off >>= 1)
        acc += __shfl_down(acc, off, 64);
    if ((t & 63) == 0) wsum[w] = acc;
    __syncthreads();
    if (t == 0) energy[b] = wsum[0] + wsum[1] + wsum[2] + wsum[3];
}

extern "C" void kernel_launch(void* const* d_in, const int* in_sizes, int n_in,
                              void* d_out, int out_size, void* d_ws, size_t ws_size,
                              hipStream_t stream) {
    // setup_inputs order:
    // 0 positions, 1 embed, 2 W1, 3 b1, 4 W2, 5 b2, 6 W3, 7 b3,
    // 8 atomic_numbers, 9 batch
    const float* embed = (const float*)d_in[1];
    const float* W1    = (const float*)d_in[2];
    const float* b1    = (const float*)d_in[3];
    const float* W2    = (const float*)d_in[4];
    const float* b2    = (const float*)d_in[5];
    const float* W3    = (const float*)d_in[6];
    const float* b3    = (const float*)d_in[7];
    const int*   z     = (const int*)d_in[8];
    const int*   batch = (const int*)d_in[9];
    const int    n     = in_sizes[8];              // 1,000,000

    const int B   = out_size - 3 * n;              // 1024
    const int nf4 = (3 * n) / 4;                   // 750,000 float4 zeros

    float*  energy  = (float*)d_out;               // [B]
    float4* forces4 = (float4*)((float*)d_out + B); // [3N], 16B-aligned (B*4=4096)
    float*  Etab    = (float*)d_ws;                // 118 floats of scratch

    mace_etab_kernel<<<NUM_EL, D_HID, 0, stream>>>(embed, W1, b1, W2, b2, W3, b3, Etab);
    mace_segsum_kernel<<<B, 256, 0, stream>>>(z, batch, Etab, energy, forces4, n, nf4);
}

// Round 3
// 14.642 us; speedup vs baseline: 4.1112x; 1.0268x over previous
//
#include <hip/hip_runtime.h>

#define D_EMB   64
#define D_HID   128
#define NUM_EL  118
#define PREP_GRID 2048

// ---------------------------------------------------------------------------
// Kernel 1 ("prep"): ALL blocks zero the force output (grid-strided float4,
// fire-and-forget stores). Blocks 0..117 additionally compute the per-element
// energy table with threads 0..127 (one per hidden unit) — latency-bound MLP
// overlapped with the store-bandwidth-bound zeroing on other waves/blocks.
// ---------------------------------------------------------------------------
__global__ __launch_bounds__(256)
void mace_prep_kernel(const float* __restrict__ embed,
                      const float* __restrict__ W1, const float* __restrict__ b1,
                      const float* __restrict__ W2, const float* __restrict__ b2,
                      const float* __restrict__ W3, const float* __restrict__ b3,
                      float* __restrict__ Etab,
                      float4* __restrict__ forces4, int nf4) {
    const int t = threadIdx.x;

    // --- zero forces (issue stores first; they retire asynchronously) ---
    const int gstride = gridDim.x * blockDim.x;
    for (int i = blockIdx.x * blockDim.x + t; i < nf4; i += gstride)
        forces4[i] = make_float4(0.f, 0.f, 0.f, 0.f);

    // --- per-element MLP on blocks 0..117 (block-uniform branch) ---
    if (blockIdx.x < NUM_EL) {
        __shared__ float h[D_EMB];
        __shared__ float x1[D_HID];
        __shared__ float wsum[2];
        const int z = blockIdx.x;

        if (t < D_EMB) h[t] = embed[z * D_EMB + t];
        __syncthreads();

        if (t < D_HID) {
            // x1 = silu(h @ W1 + b1); W1 is (64,128) row-major
            float a0 = 0.f, a1 = 0.f, a2 = 0.f, a3 = 0.f;
            #pragma unroll
            for (int k = 0; k < D_EMB; k += 4) {
                a0 = fmaf(h[k + 0], W1[(k + 0) * D_HID + t], a0);
                a1 = fmaf(h[k + 1], W1[(k + 1) * D_HID + t], a1);
                a2 = fmaf(h[k + 2], W1[(k + 2) * D_HID + t], a2);
                a3 = fmaf(h[k + 3], W1[(k + 3) * D_HID + t], a3);
            }
            const float acc = b1[t] + ((a0 + a1) + (a2 + a3));
            x1[t] = acc / (1.0f + expf(-acc));
        }
        __syncthreads();

        float r = 0.f;
        if (t < D_HID) {
            float a0 = 0.f, a1 = 0.f, a2 = 0.f, a3 = 0.f;
            #pragma unroll
            for (int k = 0; k < D_HID; k += 4) {
                a0 = fmaf(x1[k + 0], W2[(k + 0) * D_HID + t], a0);
                a1 = fmaf(x1[k + 1], W2[(k + 1) * D_HID + t], a1);
                a2 = fmaf(x1[k + 2], W2[(k + 2) * D_HID + t], a2);
                a3 = fmaf(x1[k + 3], W2[(k + 3) * D_HID + t], a3);
            }
            const float acc2 = b2[t] + ((a0 + a1) + (a2 + a3));
            const float s2 = acc2 / (1.0f + expf(-acc2));
            r = s2 * W3[t];
        }
        // waves 0,1 hold t<128; shuffle-reduce within each wave
        #pragma unroll
        for (int off = 32; off > 0; off >>= 1)
            r += __shfl_down(r, off, 64);
        if (t < D_HID && (t & 63) == 0) wsum[t >> 6] = r;
        __syncthreads();
        if (t == 0) Etab[z] = wsum[0] + wsum[1] + b3[0];
    }
}

// ---------------------------------------------------------------------------
// Cooperative 64-ary lower_bound over the sorted batch array.
// ---------------------------------------------------------------------------
__device__ __forceinline__ int lower_bound_wave(const int* __restrict__ arr,
                                                int n, int target) {
    int lo = 0, hi = n;
    const int lane = threadIdx.x & 63;
    while (hi > lo) {
        const int range = hi - lo;
        const int step  = (range + 63) >> 6;
        const int pos   = lo + lane * step;
        const bool lt   = (pos < hi) && (arr[pos] < target);
        const unsigned long long m = __ballot(lt);
        const int k = __popcll(m);
        if (k == 0) { hi = lo; break; }
        const int new_lo = lo + (k - 1) * step + 1;
        int new_hi = lo + k * step;
        if (new_hi > hi) new_hi = hi;
        lo = new_lo; hi = new_hi;
    }
    return lo;
}

// ---------------------------------------------------------------------------
// Kernel 2: one block per molecule. Wave-search segment bounds, int4-gather
// the atomic numbers, LDS-lookup the energy table, direct store (no atomics).
// ---------------------------------------------------------------------------
__global__ __launch_bounds__(256)
void mace_segsum_kernel(const int* __restrict__ z,
                        const int* __restrict__ batch,
                        const float* __restrict__ EtabG,
                        float* __restrict__ energy, int n) {
    __shared__ float etab_s[NUM_EL];
    __shared__ int   bounds[2];
    __shared__ float wsum[4];
    const int b = blockIdx.x;
    const int t = threadIdx.x;
    const int w = t >> 6;

    if (t < NUM_EL) etab_s[t] = EtabG[t];

    if (w == 0) {
        const int s = lower_bound_wave(batch, n, b);
        if ((t & 63) == 0) bounds[0] = s;
    } else if (w == 1) {
        const int e = lower_bound_wave(batch, n, b + 1);
        if ((t & 63) == 0) bounds[1] = e;
    }
    __syncthreads();

    const int start = bounds[0], end = bounds[1];
    float acc = 0.f;

    int a0 = (start + 3) & ~3;            // first 16B-aligned index
    if (a0 > end) a0 = end;
    const int a1 = (end >= a0) ? (end & ~3) : a0;  // last aligned index

    // scalar head (< 4 elems)
    if (t < a0 - start) acc += etab_s[z[start + t]];
    // scalar tail (< 4 elems)
    if (a1 >= a0 && t < end - a1) acc += etab_s[z[a1 + t]];
    // vectorized body
    const int4* __restrict__ z4 = (const int4*)z;
    for (int i4 = (a0 >> 2) + t; i4 < (a1 >> 2); i4 += 256) {
        const int4 v = z4[i4];
        acc += etab_s[v.x] + etab_s[v.y] + etab_s[v.z] + etab_s[v.w];
    }

    #pragma unroll
    for (int off = 32; off > 0; off >>= 1)
        acc += __shfl_down(acc, off, 64);
    if ((t & 63) == 0) wsum[w] = acc;
    __syncthreads();
    if (t == 0) energy[b] = wsum[0] + wsum[1] + wsum[2] + wsum[3];
}

extern "C" void kernel_launch(void* const* d_in, const int* in_sizes, int n_in,
                              void* d_out, int out_size, void* d_ws, size_t ws_size,
                              hipStream_t stream) {
    // 0 positions, 1 embed, 2 W1, 3 b1, 4 W2, 5 b2, 6 W3, 7 b3,
    // 8 atomic_numbers, 9 batch
    const float* embed = (const float*)d_in[1];
    const float* W1    = (const float*)d_in[2];
    const float* b1    = (const float*)d_in[3];
    const float* W2    = (const float*)d_in[4];
    const float* b2    = (const float*)d_in[5];
    const float* W3    = (const float*)d_in[6];
    const float* b3    = (const float*)d_in[7];
    const int*   z     = (const int*)d_in[8];
    const int*   batch = (const int*)d_in[9];
    const int    n     = in_sizes[8];               // 1,000,000

    const int B   = out_size - 3 * n;               // 1024
    const int nf4 = (3 * n) / 4;                    // 750,000

    float*  energy  = (float*)d_out;                 // [B]
    float4* forces4 = (float4*)((float*)d_out + B);  // [3N], 16B-aligned
    float*  Etab    = (float*)d_ws;                  // 118 floats

    mace_prep_kernel<<<PREP_GRID, 256, 0, stream>>>(embed, W1, b1, W2, b2, W3, b3,
                                                    Etab, forces4, nf4);
    mace_segsum_kernel<<<B, 256, 0, stream>>>(z, batch, Etab, energy, n);
}

// Round 4
// 14.104 us; speedup vs baseline: 4.2680x; 1.0382x over previous
//
#include <hip/hip_runtime.h>

#define D_EMB   64
#define D_HID   128
#define NUM_EL  118
#define PREP_GRID 2048

// ---------------------------------------------------------------------------
// Kernel 1 ("prep"):
//   (a) all blocks: zero the 12 MB force output (grid-strided float4)
//   (b) all blocks: linear-diff the sorted batch array -> starts[0..B]
//       (starts[b] = lower_bound(batch, b); each entry written by exactly
//        one thread, so no atomics / no ordering assumptions needed)
//   (c) blocks 0..117: per-element MLP -> Etab[z] (latency-bound, overlaps
//       with the bandwidth-bound work on other blocks)
// ---------------------------------------------------------------------------
__global__ __launch_bounds__(256)
void mace_prep_kernel(const float* __restrict__ embed,
                      const float* __restrict__ W1, const float* __restrict__ b1,
                      const float* __restrict__ W2, const float* __restrict__ b2,
                      const float* __restrict__ W3, const float* __restrict__ b3,
                      float* __restrict__ Etab,
                      int* __restrict__ starts,
                      const int* __restrict__ batch, int n, int B,
                      float4* __restrict__ forces4, int nf4) {
    const int t = threadIdx.x;
    const int gid = blockIdx.x * blockDim.x + t;
    const int gstride = gridDim.x * blockDim.x;

    // --- (a) zero forces ---
    for (int i = gid; i < nf4; i += gstride)
        forces4[i] = make_float4(0.f, 0.f, 0.f, 0.f);

    // --- (b) segment boundaries from sorted batch ---
    for (int i = gid; i < n - 1; i += gstride) {
        const int c0 = batch[i];
        const int c1 = batch[i + 1];
        if (c0 != c1) {
            for (int b = c0 + 1; b <= c1; ++b) starts[b] = i + 1;
        }
    }
    if (gid == 0) {
        const int first = batch[0], last = batch[n - 1];
        for (int b = 0; b <= first; ++b) starts[b] = 0;
        for (int b = last + 1; b <= B; ++b) starts[b] = n;
    }

    // --- (c) per-element MLP on blocks 0..117 ---
    if (blockIdx.x < NUM_EL) {
        __shared__ float h[D_EMB];
        __shared__ float x1[D_HID];
        __shared__ float wsum[2];
        const int zz = blockIdx.x;

        if (t < D_EMB) h[t] = embed[zz * D_EMB + t];
        __syncthreads();

        if (t < D_HID) {
            float a0 = 0.f, a1 = 0.f, a2 = 0.f, a3 = 0.f;
            #pragma unroll
            for (int k = 0; k < D_EMB; k += 4) {
                a0 = fmaf(h[k + 0], W1[(k + 0) * D_HID + t], a0);
                a1 = fmaf(h[k + 1], W1[(k + 1) * D_HID + t], a1);
                a2 = fmaf(h[k + 2], W1[(k + 2) * D_HID + t], a2);
                a3 = fmaf(h[k + 3], W1[(k + 3) * D_HID + t], a3);
            }
            const float acc = b1[t] + ((a0 + a1) + (a2 + a3));
            x1[t] = acc / (1.0f + expf(-acc));
        }
        __syncthreads();

        float r = 0.f;
        if (t < D_HID) {
            float a0 = 0.f, a1 = 0.f, a2 = 0.f, a3 = 0.f;
            #pragma unroll
            for (int k = 0; k < D_HID; k += 4) {
                a0 = fmaf(x1[k + 0], W2[(k + 0) * D_HID + t], a0);
                a1 = fmaf(x1[k + 1], W2[(k + 1) * D_HID + t], a1);
                a2 = fmaf(x1[k + 2], W2[(k + 2) * D_HID + t], a2);
                a3 = fmaf(x1[k + 3], W2[(k + 3) * D_HID + t], a3);
            }
            const float acc2 = b2[t] + ((a0 + a1) + (a2 + a3));
            const float s2 = acc2 / (1.0f + expf(-acc2));
            r = s2 * W3[t];
        }
        #pragma unroll
        for (int off = 32; off > 0; off >>= 1)
            r += __shfl_down(r, off, 64);
        if (t < D_HID && (t & 63) == 0) wsum[t >> 6] = r;
        __syncthreads();
        if (t == 0) Etab[zz] = wsum[0] + wsum[1] + b3[0];
    }
}

// ---------------------------------------------------------------------------
// Kernel 2: one block per molecule. Bounds are precomputed (two broadcast
// loads), body is a coalesced int4 gather of atomic numbers + LDS table
// lookup + wave reduce + direct store. No search, no atomics.
// ---------------------------------------------------------------------------
__global__ __launch_bounds__(256)
void mace_segsum_kernel(const int* __restrict__ z,
                        const int* __restrict__ starts,
                        const float* __restrict__ EtabG,
                        float* __restrict__ energy) {
    __shared__ float etab_s[NUM_EL];
    __shared__ float wsum[4];
    const int b = blockIdx.x;
    const int t = threadIdx.x;
    const int w = t >> 6;

    if (t < NUM_EL) etab_s[t] = EtabG[t];
    const int start = starts[b];        // uniform -> broadcast from one line
    const int end   = starts[b + 1];
    __syncthreads();

    float acc = 0.f;

    int a0 = (start + 3) & ~3;                      // first 16B-aligned idx
    if (a0 > end) a0 = end;
    const int a1 = (end >= a0) ? (end & ~3) : a0;   // aligned end

    if (t < a0 - start) acc += etab_s[z[start + t]];        // head (<4)
    if (a1 >= a0 && t < end - a1) acc += etab_s[z[a1 + t]]; // tail (<4)

    const int4* __restrict__ z4 = (const int4*)z;
    for (int i4 = (a0 >> 2) + t; i4 < (a1 >> 2); i4 += 256) {
        const int4 v = z4[i4];
        acc += (etab_s[v.x] + etab_s[v.y]) + (etab_s[v.z] + etab_s[v.w]);
    }

    #pragma unroll
    for (int off = 32; off > 0; off >>= 1)
        acc += __shfl_down(acc, off, 64);
    if ((t & 63) == 0) wsum[w] = acc;
    __syncthreads();
    if (t == 0) energy[b] = (wsum[0] + wsum[1]) + (wsum[2] + wsum[3]);
}

extern "C" void kernel_launch(void* const* d_in, const int* in_sizes, int n_in,
                              void* d_out, int out_size, void* d_ws, size_t ws_size,
                              hipStream_t stream) {
    // 0 positions, 1 embed, 2 W1, 3 b1, 4 W2, 5 b2, 6 W3, 7 b3,
    // 8 atomic_numbers, 9 batch
    const float* embed = (const float*)d_in[1];
    const float* W1    = (const float*)d_in[2];
    const float* b1    = (const float*)d_in[3];
    const float* W2    = (const float*)d_in[4];
    const float* b2    = (const float*)d_in[5];
    const float* W3    = (const float*)d_in[6];
    const float* b3    = (const float*)d_in[7];
    const int*   z     = (const int*)d_in[8];
    const int*   batch = (const int*)d_in[9];
    const int    n     = in_sizes[8];               // 1,000,000

    const int B   = out_size - 3 * n;               // 1024
    const int nf4 = (3 * n) / 4;                    // 750,000

    float*  energy  = (float*)d_out;                 // [B]
    float4* forces4 = (float4*)((float*)d_out + B);  // [3N], 16B-aligned
    float*  Etab    = (float*)d_ws;                  // 118 floats
    int*    starts  = (int*)d_ws + 128;              // B+1 ints

    mace_prep_kernel<<<PREP_GRID, 256, 0, stream>>>(embed, W1, b1, W2, b2, W3, b3,
                                                    Etab, starts, batch, n, B,
                                                    forces4, nf4);
    mace_segsum_kernel<<<B, 256, 0, stream>>>(z, starts, Etab, energy);
}